// Round 6
// baseline (801.544 us; speedup 1.0000x reference)
//
#include <hip/hip_runtime.h>

#define NN 50000
#define EE 800000
// IN=256, EMB1=128, EMB2=64, L1=64

// ---------------- CSR build ----------------
__global__ void hist_k(const int* __restrict__ row, int* __restrict__ deg, int E) {
    int e = blockIdx.x * blockDim.x + threadIdx.x;
    if (e < E) atomicAdd(&deg[row[e]], 1);
}

__global__ __launch_bounds__(1024) void scan_k(const int* __restrict__ deg, int* __restrict__ ptr,
                                               int* __restrict__ cursor, int N) {
    __shared__ int sm[1024];
    int t = threadIdx.x;
    int chunk = (N + 1023) / 1024;
    int lo = t * chunk, hi = lo + chunk; if (hi > N) hi = N;
    int s = 0;
    for (int i = lo; i < hi; i++) s += deg[i];
    sm[t] = s;
    __syncthreads();
    for (int off = 1; off < 1024; off <<= 1) {
        int v = (t >= off) ? sm[t - off] : 0;
        __syncthreads();
        sm[t] += v;
        __syncthreads();
    }
    int run = (t == 0) ? 0 : sm[t - 1];
    for (int i = lo; i < hi; i++) { ptr[i] = run; cursor[i] = run; run += deg[i]; }
    if (t == 1023) ptr[N] = sm[1023];
}

__global__ void place_k(const int* __restrict__ row, const int* __restrict__ col,
                        int* __restrict__ cursor, int* __restrict__ ccol, int E) {
    int e = blockIdx.x * blockDim.x + threadIdx.x;
    if (e >= E) return;
    int p = atomicAdd(&cursor[row[e]], 1);
    ccol[p] = col[e];
}

// ---------------- combined k4-vectorized weight builds ----------------
// layout: wt[(k>>2)*(J*4) + j*4 + (k&3)]  -> float4 per (k4, j) holds k=4k4..4k4+3
// wt1: J=256 (j<128: w_rel1, else w_root1), K=256
// wt3: J=192 (w_rel_mu | w_root_mu | w_std), K=128
// wtg: J=128 (w_rel_g1 | w_root_g1), K=64
__global__ void transpose_all(const float* __restrict__ w_rel1, const float* __restrict__ w_root1,
                              const float* __restrict__ w_rel_mu, const float* __restrict__ w_root_mu,
                              const float* __restrict__ w_std,
                              const float* __restrict__ w_rel_g1, const float* __restrict__ w_root_g1,
                              float* __restrict__ wt1, float* __restrict__ wt3,
                              float* __restrict__ wtg) {
    int idx = blockIdx.x * 256 + threadIdx.x;
    if (idx < 65536) {
        int k = idx >> 8, j = idx & 255;
        int o = (k >> 2) * 1024 + j * 4 + (k & 3);
        wt1[o] = (j < 128) ? w_rel1[j * 256 + k] : w_root1[(j - 128) * 256 + k];
    } else if (idx < 90112) {
        int q = idx - 65536; int k = q / 192, j = q % 192;
        int o = (k >> 2) * 768 + j * 4 + (k & 3);
        wt3[o] = (j < 64) ? w_rel_mu[j * 128 + k]
               : (j < 128) ? w_root_mu[(j - 64) * 128 + k]
                           : w_std[(j - 128) * 128 + k];
    } else if (idx < 98304) {
        int q = idx - 90112; int k = q >> 7, j = q & 127;
        int o = (k >> 2) * 512 + j * 4 + (k & 3);
        wtg[o] = (j < 64) ? w_rel_g1[j * 64 + k] : w_root_g1[(j - 64) * 64 + k];
    }
}

// ---------------- conv1 GEMM: [xr | xroot] = x @ wt1 ; 16 nodes/block, 4 cols/thread ----------------
// __launch_bounds__(64, 2): VGPR cap 256 — room for 64 fp32 accumulators + 16 weight
// regs without scratch spill (rounds 3-5 had VGPR_Count < live accs -> in-loop spills).
__global__ __launch_bounds__(64, 2) void mm256_k(const float* __restrict__ x,
        const float4* __restrict__ wt4,
        float* __restrict__ xr, float* __restrict__ xroot) {
    int t = threadIdx.x;
    int n0 = blockIdx.x * 16;
    const float4* xp = reinterpret_cast<const float4*>(x + (size_t)n0 * 256);
    float a0[16] = {}, a1[16] = {}, a2[16] = {}, a3[16] = {};
    for (int k4 = 0; k4 < 64; k4++) {
        float4 w0 = wt4[k4 * 256 + t];
        float4 w1 = wt4[k4 * 256 + t + 64];
        float4 w2 = wt4[k4 * 256 + t + 128];
        float4 w3 = wt4[k4 * 256 + t + 192];
#pragma unroll
        for (int n = 0; n < 16; n++) {
            float4 xv = xp[n * 64 + k4];
            a0[n] = fmaf(xv.x, w0.x, a0[n]); a0[n] = fmaf(xv.y, w0.y, a0[n]);
            a0[n] = fmaf(xv.z, w0.z, a0[n]); a0[n] = fmaf(xv.w, w0.w, a0[n]);
            a1[n] = fmaf(xv.x, w1.x, a1[n]); a1[n] = fmaf(xv.y, w1.y, a1[n]);
            a1[n] = fmaf(xv.z, w1.z, a1[n]); a1[n] = fmaf(xv.w, w1.w, a1[n]);
            a2[n] = fmaf(xv.x, w2.x, a2[n]); a2[n] = fmaf(xv.y, w2.y, a2[n]);
            a2[n] = fmaf(xv.z, w2.z, a2[n]); a2[n] = fmaf(xv.w, w2.w, a2[n]);
            a3[n] = fmaf(xv.x, w3.x, a3[n]); a3[n] = fmaf(xv.y, w3.y, a3[n]);
            a3[n] = fmaf(xv.z, w3.z, a3[n]); a3[n] = fmaf(xv.w, w3.w, a3[n]);
        }
    }
#pragma unroll
    for (int n = 0; n < 16; n++) {
        size_t o = (size_t)(n0 + n) * 128;
        xr[o + t]         = a0[n];
        xr[o + t + 64]    = a1[n];
        xroot[o + t]      = a2[n];
        xroot[o + t + 64] = a3[n];
    }
}

// ---------------- fused agg(width128) + h = lrelu(agg + xroot + b1), float2 lanes ----------------
__global__ __launch_bounds__(64) void aggh_k(const float2* __restrict__ xr2,
        const float2* __restrict__ xroot2, const float* __restrict__ b1,
        const int* __restrict__ ptr, const int* __restrict__ ccol,
        float2* __restrict__ h2) {
    int r = blockIdx.x, j = threadIdx.x;   // j = float2 column pair (0..63)
    int beg = ptr[r], end = ptr[r + 1];
    float sx0 = 0.f, sy0 = 0.f, sx1 = 0.f, sy1 = 0.f;
    float sx2 = 0.f, sy2 = 0.f, sx3 = 0.f, sy3 = 0.f;
    int e = beg;
    for (; e + 4 <= end; e += 4) {
        int c0 = ccol[e], c1 = ccol[e + 1], c2 = ccol[e + 2], c3 = ccol[e + 3];
        float2 v0 = xr2[(size_t)c0 * 64 + j];
        float2 v1 = xr2[(size_t)c1 * 64 + j];
        float2 v2 = xr2[(size_t)c2 * 64 + j];
        float2 v3 = xr2[(size_t)c3 * 64 + j];
        sx0 += v0.x; sy0 += v0.y; sx1 += v1.x; sy1 += v1.y;
        sx2 += v2.x; sy2 += v2.y; sx3 += v3.x; sy3 += v3.y;
    }
    for (; e < end; e++) {
        float2 v = xr2[(size_t)ccol[e] * 64 + j];
        sx0 += v.x; sy0 += v.y;
    }
    float2 xo = xroot2[(size_t)r * 64 + j];
    float hx = (sx0 + sx1) + (sx2 + sx3) + xo.x + b1[2 * j];
    float hy = (sy0 + sy1) + (sy2 + sy3) + xo.y + b1[2 * j + 1];
    hx = hx > 0.f ? hx : 0.2f * hx;
    hy = hy > 0.f ? hy : 0.2f * hy;
    h2[(size_t)r * 64 + j] = make_float2(hx, hy);
}

// ---------------- triple matmul: hr|hmu|hstd = h @ wt3 ; 16 nodes/block, 3 cols/thread ----------------
__global__ __launch_bounds__(64, 2) void mm128x3_k(const float* __restrict__ h,
        const float4* __restrict__ wt4,
        float* __restrict__ hr, float* __restrict__ hmu, float* __restrict__ hstd) {
    int t = threadIdx.x;
    int n0 = blockIdx.x * 16;
    const float4* hp = reinterpret_cast<const float4*>(h + (size_t)n0 * 128);
    float a0[16] = {}, a1[16] = {}, a2[16] = {};
    for (int k4 = 0; k4 < 32; k4++) {
        float4 w0 = wt4[k4 * 192 + t];
        float4 w1 = wt4[k4 * 192 + t + 64];
        float4 w2 = wt4[k4 * 192 + t + 128];
#pragma unroll
        for (int n = 0; n < 16; n++) {
            float4 hv = hp[n * 32 + k4];
            a0[n] = fmaf(hv.x, w0.x, a0[n]); a0[n] = fmaf(hv.y, w0.y, a0[n]);
            a0[n] = fmaf(hv.z, w0.z, a0[n]); a0[n] = fmaf(hv.w, w0.w, a0[n]);
            a1[n] = fmaf(hv.x, w1.x, a1[n]); a1[n] = fmaf(hv.y, w1.y, a1[n]);
            a1[n] = fmaf(hv.z, w1.z, a1[n]); a1[n] = fmaf(hv.w, w1.w, a1[n]);
            a2[n] = fmaf(hv.x, w2.x, a2[n]); a2[n] = fmaf(hv.y, w2.y, a2[n]);
            a2[n] = fmaf(hv.z, w2.z, a2[n]); a2[n] = fmaf(hv.w, w2.w, a2[n]);
        }
    }
#pragma unroll
    for (int n = 0; n < 16; n++) {
        size_t o = (size_t)(n0 + n) * 64 + t;
        hr[o] = a0[n]; hmu[o] = a1[n]; hstd[o] = a2[n];
    }
}

// ---------------- z-stage: agg(hr) + tanh/exp + outputs + row norm (4-deep MLP) ----------------
__global__ __launch_bounds__(64) void aggz_k(const float* __restrict__ hr,
        const float* __restrict__ hmu, const float* __restrict__ hstd,
        const float* __restrict__ b_mu, const float* __restrict__ b_std,
        const int* __restrict__ ptr, const int* __restrict__ ccol,
        float* __restrict__ z, float* __restrict__ out_z, float* __restrict__ out_zmu,
        float* __restrict__ out_zstd, float* __restrict__ nrm) {
    int r = blockIdx.x, j = threadIdx.x;
    int beg = ptr[r], end = ptr[r + 1];
    float a0 = 0.f, a1 = 0.f, a2 = 0.f, a3 = 0.f;
    int e = beg;
    for (; e + 4 <= end; e += 4) {
        int c0 = ccol[e], c1 = ccol[e + 1], c2 = ccol[e + 2], c3 = ccol[e + 3];
        a0 += hr[(size_t)c0 * 64 + j];
        a1 += hr[(size_t)c1 * 64 + j];
        a2 += hr[(size_t)c2 * 64 + j];
        a3 += hr[(size_t)c3 * 64 + j];
    }
    for (; e < end; e++) a0 += hr[(size_t)ccol[e] * 64 + j];
    float acc = (a0 + a1) + (a2 + a3);
    float zmu = tanhf(acc + hmu[(size_t)r * 64 + j] + b_mu[j]);
    float zls = tanhf(hstd[(size_t)r * 64 + j] + b_std[j]);
    float zstd = expf(zls);
    size_t o = (size_t)r * 64 + j;
    z[o] = zmu; out_z[o] = zmu; out_zmu[o] = zmu; out_zstd[o] = zstd;
    float s = zmu * zmu;
    s += __shfl_xor(s, 1); s += __shfl_xor(s, 2); s += __shfl_xor(s, 4);
    s += __shfl_xor(s, 8); s += __shfl_xor(s, 16); s += __shfl_xor(s, 32);
    if (j == 0) nrm[r] = fmaxf(sqrtf(s), 1e-8f);
}

// ---------------- edge cosine: 16 lanes per edge ----------------
__global__ __launch_bounds__(256) void edge_k(const float* __restrict__ z, const float* __restrict__ nrm,
        const int* __restrict__ row, const int* __restrict__ col, float* __restrict__ out, int E) {
    int t = threadIdx.x;
    int sub = t >> 4, off = t & 15;
    int e = blockIdx.x * 16 + sub;
    if (e >= E) return;
    int r = row[e], c = col[e];
    const float4* a = reinterpret_cast<const float4*>(z + (size_t)r * 64);
    const float4* b = reinterpret_cast<const float4*>(z + (size_t)c * 64);
    float4 av = a[off], bv = b[off];
    float s = av.x * bv.x + av.y * bv.y + av.z * bv.z + av.w * bv.w;
    s += __shfl_xor(s, 1); s += __shfl_xor(s, 2); s += __shfl_xor(s, 4); s += __shfl_xor(s, 8);
    if (off == 0) out[e] = s / (nrm[r] * nrm[c]);
}

// ---------------- dual matmul: zr|zroot = z @ wtg ; 16 nodes/block, 2 cols/thread ----------------
__global__ __launch_bounds__(64, 2) void mm64x2_k(const float* __restrict__ z,
        const float4* __restrict__ wt4,
        float* __restrict__ zr, float* __restrict__ zroot) {
    int t = threadIdx.x;
    int n0 = blockIdx.x * 16;
    const float4* zp = reinterpret_cast<const float4*>(z + (size_t)n0 * 64);
    float a0[16] = {}, a1[16] = {};
    for (int k4 = 0; k4 < 16; k4++) {
        float4 w0 = wt4[k4 * 128 + t];
        float4 w1 = wt4[k4 * 128 + t + 64];
#pragma unroll
        for (int n = 0; n < 16; n++) {
            float4 zv = zp[n * 16 + k4];
            a0[n] = fmaf(zv.x, w0.x, a0[n]); a0[n] = fmaf(zv.y, w0.y, a0[n]);
            a0[n] = fmaf(zv.z, w0.z, a0[n]); a0[n] = fmaf(zv.w, w0.w, a0[n]);
            a1[n] = fmaf(zv.x, w1.x, a1[n]); a1[n] = fmaf(zv.y, w1.y, a1[n]);
            a1[n] = fmaf(zv.z, w1.z, a1[n]); a1[n] = fmaf(zv.w, w1.w, a1[n]);
        }
    }
#pragma unroll
    for (int n = 0; n < 16; n++) {
        size_t o = (size_t)(n0 + n) * 64 + t;
        zr[o] = a0[n]; zroot[o] = a1[n];
    }
}

// ---------------- g1-stage (4-deep MLP) ----------------
__global__ __launch_bounds__(64) void g1gate_k(const float* __restrict__ zr, const float* __restrict__ zroot,
        const float* __restrict__ b_g1, const float* __restrict__ w_rel_g2,
        const float* __restrict__ w_root_g2,
        const int* __restrict__ ptr, const int* __restrict__ ccol,
        float* __restrict__ g1r, float* __restrict__ groot) {
    int r = blockIdx.x, j = threadIdx.x;
    int beg = ptr[r], end = ptr[r + 1];
    float a0 = 0.f, a1 = 0.f, a2 = 0.f, a3 = 0.f;
    int e = beg;
    for (; e + 4 <= end; e += 4) {
        int c0 = ccol[e], c1 = ccol[e + 1], c2 = ccol[e + 2], c3 = ccol[e + 3];
        a0 += zr[(size_t)c0 * 64 + j];
        a1 += zr[(size_t)c1 * 64 + j];
        a2 += zr[(size_t)c2 * 64 + j];
        a3 += zr[(size_t)c3 * 64 + j];
    }
    for (; e < end; e++) a0 += zr[(size_t)ccol[e] * 64 + j];
    float g = (a0 + a1) + (a2 + a3) + zroot[(size_t)r * 64 + j] + b_g1[j];
    g = g > 0.f ? g : 0.2f * g;
    float sr = g * w_rel_g2[j];
    float so = g * w_root_g2[j];
    sr += __shfl_xor(sr, 1); sr += __shfl_xor(sr, 2); sr += __shfl_xor(sr, 4);
    sr += __shfl_xor(sr, 8); sr += __shfl_xor(sr, 16); sr += __shfl_xor(sr, 32);
    so += __shfl_xor(so, 1); so += __shfl_xor(so, 2); so += __shfl_xor(so, 4);
    so += __shfl_xor(so, 8); so += __shfl_xor(so, 16); so += __shfl_xor(so, 32);
    if (j == 0) { g1r[r] = sr; groot[r] = so; }
}

// ---------------- gate assembly + partial max ----------------
__global__ __launch_bounds__(256) void gateagg_k(const float* __restrict__ g1r,
        const float* __restrict__ groot, const float* __restrict__ b_g2,
        const int* __restrict__ ptr, const int* __restrict__ ccol,
        float* __restrict__ gate, float* __restrict__ pmax, int N) {
    __shared__ float sm[256];
    float b = b_g2[0];
    float m = -3.4e38f;
    for (int r = blockIdx.x * blockDim.x + threadIdx.x; r < N; r += gridDim.x * blockDim.x) {
        int beg = ptr[r], end = ptr[r + 1];
        float s0 = 0.f, s1 = 0.f, s2 = 0.f, s3 = 0.f;
        int e = beg;
        for (; e + 4 <= end; e += 4) {
            s0 += g1r[ccol[e]]; s1 += g1r[ccol[e + 1]];
            s2 += g1r[ccol[e + 2]]; s3 += g1r[ccol[e + 3]];
        }
        for (; e < end; e++) s0 += g1r[ccol[e]];
        float g = (s0 + s1) + (s2 + s3) + groot[r] + b;
        gate[r] = g;
        m = fmaxf(m, g);
    }
    sm[threadIdx.x] = m;
    __syncthreads();
    for (int s2 = 128; s2 > 0; s2 >>= 1) {
        if (threadIdx.x < s2) sm[threadIdx.x] = fmaxf(sm[threadIdx.x], sm[threadIdx.x + s2]);
        __syncthreads();
    }
    if (threadIdx.x == 0) pmax[blockIdx.x] = sm[0];
}

__global__ void reduce_max_final(const float* __restrict__ pmax, float* __restrict__ smax) {
    float m = pmax[threadIdx.x];   // 64 threads, 64 partials
    for (int o = 32; o > 0; o >>= 1) m = fmaxf(m, __shfl_down(m, o));
    if (threadIdx.x == 0) smax[0] = m;
}

__global__ __launch_bounds__(256) void pooled_kernel(const float* __restrict__ gate,
        const float* __restrict__ smax, const float* __restrict__ z,
        float* __restrict__ pooled_num, float* __restrict__ wsum, int N) {
    int tid = threadIdx.x;
    int sub = tid >> 6, j = tid & 63;
    float mx = smax[0];
    float acc = 0.f, wsl = 0.f;
    for (int n = blockIdx.x * 4 + sub; n < N; n += gridDim.x * 4) {
        float w = expf(gate[n] - mx);
        acc = fmaf(w, z[(size_t)n * 64 + j], acc);
        if (j == 0) wsl += w;
    }
    __shared__ float lp[4][64];
    __shared__ float lw[4];
    lp[sub][j] = acc;
    if (j == 0) lw[sub] = wsl;
    __syncthreads();
    if (sub == 0) {
        float t = lp[0][j] + lp[1][j] + lp[2][j] + lp[3][j];
        atomicAdd(&pooled_num[j], t);
        if (j == 0) atomicAdd(wsum, lw[0] + lw[1] + lw[2] + lw[3]);
    }
}

__global__ void final_kernel(const float* __restrict__ pooled_num, const float* __restrict__ wsum,
                             const float* __restrict__ w_cls1, const float* __restrict__ b_cls1,
                             const float* __restrict__ w_cls2, const float* __restrict__ b_cls2,
                             const float* __restrict__ log_std,
                             float* __restrict__ out_y, float* __restrict__ out_wstd) {
    __shared__ float sp[64];
    __shared__ float st[64];
    int j = threadIdx.x;   // 64
    sp[j] = pooled_num[j] / wsum[0];
    __syncthreads();
    float acc = 0.f;
    const float* w = w_cls1 + j * 64;
#pragma unroll
    for (int k = 0; k < 64; k++) acc = fmaf(sp[k], w[k], acc);
    acc += b_cls1[j];
    st[j] = acc > 0.f ? acc : 0.2f * acc;
    __syncthreads();
    if (j == 0) {
        float l0 = b_cls2[0], l1 = b_cls2[1];
        for (int k = 0; k < 64; k++) {
            l0 = fmaf(st[k], w_cls2[k], l0);
            l1 = fmaf(st[k], w_cls2[64 + k], l1);
        }
        float m = fmaxf(l0, l1);
        float e0 = expf(l0 - m), e1 = expf(l1 - m);
        float s = e0 + e1;
        out_y[0] = e0 / s;
        out_y[1] = e1 / s;
        out_wstd[0] = expf(log_std[0]);
    }
}

extern "C" void kernel_launch(void* const* d_in, const int* in_sizes, int n_in,
                              void* d_out, int out_size, void* d_ws, size_t ws_size,
                              hipStream_t stream) {
    const int N = NN, E = EE;
    const float* x        = (const float*)d_in[0];
    const int*   row      = (const int*)d_in[1];
    const int*   col      = (const int*)d_in[2];
    const float* w_rel1   = (const float*)d_in[3];
    const float* w_root1  = (const float*)d_in[4];
    const float* b1       = (const float*)d_in[5];
    const float* w_rel_mu = (const float*)d_in[6];
    const float* w_root_mu= (const float*)d_in[7];
    const float* b_mu     = (const float*)d_in[8];
    const float* w_std    = (const float*)d_in[9];
    const float* b_std    = (const float*)d_in[10];
    const float* w_rel_g1 = (const float*)d_in[11];
    const float* w_root_g1= (const float*)d_in[12];
    const float* b_g1     = (const float*)d_in[13];
    const float* w_rel_g2 = (const float*)d_in[14];
    const float* w_root_g2= (const float*)d_in[15];
    const float* b_g2     = (const float*)d_in[16];
    const float* w_cls1   = (const float*)d_in[17];
    const float* b_cls1   = (const float*)d_in[18];
    const float* w_cls2   = (const float*)d_in[19];
    const float* b_cls2   = (const float*)d_in[20];
    const float* log_std  = (const float*)d_in[21];

    float* out = (float*)d_out;
    const long long OFF_WMU  = 2;
    const long long OFF_WSTD = 2 + (long long)E;
    const long long OFF_Z    = 3 + (long long)E;
    const long long OFF_ZMU  = OFF_Z + (long long)N * 64;
    const long long OFF_ZSTD = OFF_ZMU + (long long)N * 64;

    // ---- workspace layout (floats), ~95 MB total ----
    float* wsp = (float*)d_ws;
    float* R0   = wsp;                             // N*128 : xr    -> hstd (lo N*64)
    float* R1   = R0 + (size_t)N * 128;            // N*128 : xroot -> [hr | hmu]
    float* R2   = R1 + (size_t)N * 128;            // N*128 : h     -> [zr | zroot]
    float* R3   = R2 + (size_t)N * 128;            // N*64  : z
    float* R4   = R3 + (size_t)N * 64;             // 4N    : nrm, g1r, groot, gate
    float* R5   = R4 + (size_t)4 * N;              // 256   : pmax | smax | pooled | wsum
    float* wt1  = R5 + 256;                        // 65536
    float* wt3  = wt1 + 65536;                     // 24576
    float* wtg  = wt3 + 24576;                     // 8192
    int*   deg    = (int*)(wtg + 8192);            // N
    int*   ptr    = deg + N;                       // N+1 (pad 64)
    int*   cursor = ptr + N + 64;                  // N
    int*   ccol   = cursor + N;                    // E

    float* xr    = R0;
    float* hstd  = R0;
    float* xroot = R1;
    float* hr    = R1;
    float* hmu   = R1 + (size_t)N * 64;
    float* h     = R2;
    float* zr    = R2;
    float* zroot = R2 + (size_t)N * 64;
    float* zbuf  = R3;
    float* nrm   = R4;
    float* g1r   = R4 + N;
    float* groot = R4 + 2 * (size_t)N;
    float* gate  = R4 + 3 * (size_t)N;
    float* pmax  = R5;
    float* smax  = R5 + 64;
    float* pooled= R5 + 128;
    float* wsum  = R5 + 192;

    // ---- CSR build (shared by all 4 graph convs) ----
    hipMemsetAsync(deg, 0, (size_t)N * 4, stream);
    hist_k<<<(E + 255) / 256, 256, 0, stream>>>(row, deg, E);
    scan_k<<<1, 1024, 0, stream>>>(deg, ptr, cursor, N);
    place_k<<<(E + 255) / 256, 256, 0, stream>>>(row, col, cursor, ccol, E);

    // ---- combined transposed weights (k4-vectorized) ----
    transpose_all<<<384, 256, 0, stream>>>(w_rel1, w_root1, w_rel_mu, w_root_mu, w_std,
                                           w_rel_g1, w_root_g1, wt1, wt3, wtg);

    // ---- conv1 ----
    mm256_k<<<N / 16, 64, 0, stream>>>(x, (const float4*)wt1, xr, xroot);
    aggh_k<<<N, 64, 0, stream>>>((const float2*)xr, (const float2*)xroot, b1, ptr, ccol,
                                 (float2*)h);

    // ---- conv2 products ----
    mm128x3_k<<<N / 16, 64, 0, stream>>>(h, (const float4*)wt3, hr, hmu, hstd);

    // ---- z-stage (agg + tanh + outputs + norms) ----
    aggz_k<<<N, 64, 0, stream>>>(hr, hmu, hstd, b_mu, b_std, ptr, ccol,
                                 zbuf, out + OFF_Z, out + OFF_ZMU, out + OFF_ZSTD, nrm);

    // ---- per-edge cosine similarity ----
    edge_k<<<(E + 15) / 16, 256, 0, stream>>>(zbuf, nrm, row, col, out + OFF_WMU, E);

    // ---- attention pooling path ----
    mm64x2_k<<<N / 16, 64, 0, stream>>>(zbuf, (const float4*)wtg, zr, zroot);
    g1gate_k<<<N, 64, 0, stream>>>(zr, zroot, b_g1, w_rel_g2, w_root_g2, ptr, ccol, g1r, groot);
    gateagg_k<<<64, 256, 0, stream>>>(g1r, groot, b_g2, ptr, ccol, gate, pmax, N);
    reduce_max_final<<<1, 64, 0, stream>>>(pmax, smax);
    hipMemsetAsync(pooled, 0, 65 * 4, stream);
    pooled_kernel<<<128, 256, 0, stream>>>(gate, smax, zbuf, pooled, wsum, N);

    // ---- classifier + scalars ----
    final_kernel<<<1, 64, 0, stream>>>(pooled, wsum, w_cls1, b_cls1, w_cls2, b_cls2, log_std,
                                       out, out + OFF_WSTD);
}

// Round 7
// 755.768 us; speedup vs baseline: 1.0606x; 1.0606x over previous
//
#include <hip/hip_runtime.h>

#define NN 50000
#define EE 800000
// IN=256, EMB1=128, EMB2=64, L1=64

// ---------------- CSR build ----------------
__global__ void hist_k(const int* __restrict__ row, int* __restrict__ deg, int E) {
    int e = blockIdx.x * blockDim.x + threadIdx.x;
    if (e < E) atomicAdd(&deg[row[e]], 1);
}

__global__ __launch_bounds__(1024) void scan_k(const int* __restrict__ deg, int* __restrict__ ptr,
                                               int* __restrict__ cursor, int N) {
    __shared__ int sm[1024];
    int t = threadIdx.x;
    int chunk = (N + 1023) / 1024;
    int lo = t * chunk, hi = lo + chunk; if (hi > N) hi = N;
    int s = 0;
    for (int i = lo; i < hi; i++) s += deg[i];
    sm[t] = s;
    __syncthreads();
    for (int off = 1; off < 1024; off <<= 1) {
        int v = (t >= off) ? sm[t - off] : 0;
        __syncthreads();
        sm[t] += v;
        __syncthreads();
    }
    int run = (t == 0) ? 0 : sm[t - 1];
    for (int i = lo; i < hi; i++) { ptr[i] = run; cursor[i] = run; run += deg[i]; }
    if (t == 1023) ptr[N] = sm[1023];
}

__global__ void place_k(const int* __restrict__ row, const int* __restrict__ col,
                        int* __restrict__ cursor, int* __restrict__ ccol, int E) {
    int e = blockIdx.x * blockDim.x + threadIdx.x;
    if (e >= E) return;
    int p = atomicAdd(&cursor[row[e]], 1);
    ccol[p] = col[e];
}

// ---------------- combined k4-vectorized weight builds ----------------
// layout: wt[(k>>2)*(J*4) + j*4 + (k&3)]  -> float4 per (k4, j) holds k=4k4..4k4+3
__global__ void transpose_all(const float* __restrict__ w_rel1, const float* __restrict__ w_root1,
                              const float* __restrict__ w_rel_mu, const float* __restrict__ w_root_mu,
                              const float* __restrict__ w_std,
                              const float* __restrict__ w_rel_g1, const float* __restrict__ w_root_g1,
                              float* __restrict__ wt1, float* __restrict__ wt3,
                              float* __restrict__ wtg) {
    int idx = blockIdx.x * 256 + threadIdx.x;
    if (idx < 65536) {
        int k = idx >> 8, j = idx & 255;
        int o = (k >> 2) * 1024 + j * 4 + (k & 3);
        wt1[o] = (j < 128) ? w_rel1[j * 256 + k] : w_root1[(j - 128) * 256 + k];
    } else if (idx < 90112) {
        int q = idx - 65536; int k = q / 192, j = q % 192;
        int o = (k >> 2) * 768 + j * 4 + (k & 3);
        wt3[o] = (j < 64) ? w_rel_mu[j * 128 + k]
               : (j < 128) ? w_root_mu[(j - 64) * 128 + k]
                           : w_std[(j - 128) * 128 + k];
    } else if (idx < 98304) {
        int q = idx - 90112; int k = q >> 7, j = q & 127;
        int o = (k >> 2) * 512 + j * 4 + (k & 3);
        wtg[o] = (j < 64) ? w_rel_g1[j * 64 + k] : w_root_g1[(j - 64) * 64 + k];
    }
}

// ---------------- conv1 GEMM: [xr | xroot] = x @ wt1 ; 16 nodes/block, LDS-staged x ----------------
// x-tile (16x256 = 16 KB) staged in LDS: k-loop x reads are ds_read (lgkm queue),
// only weight loads (L2-hit, coalesced) remain on vmcnt -> latency hidden.
__global__ __launch_bounds__(64) void mm256_k(const float* __restrict__ x,
        const float4* __restrict__ wt4,
        float* __restrict__ xr, float* __restrict__ xroot) {
    __shared__ float4 sx4[1024];   // 16 nodes x 64 float4
    int t = threadIdx.x;
    int n0 = blockIdx.x * 16;
    const float4* xg = reinterpret_cast<const float4*>(x + (size_t)n0 * 256);
#pragma unroll
    for (int i = 0; i < 16; i++) sx4[i * 64 + t] = xg[i * 64 + t];
    __syncthreads();
    float a0[16] = {}, a1[16] = {}, a2[16] = {}, a3[16] = {};
    for (int k4 = 0; k4 < 64; k4++) {
        float4 w0 = wt4[k4 * 256 + t];
        float4 w1 = wt4[k4 * 256 + t + 64];
        float4 w2 = wt4[k4 * 256 + t + 128];
        float4 w3 = wt4[k4 * 256 + t + 192];
#pragma unroll
        for (int n = 0; n < 16; n++) {
            float4 xv = sx4[n * 64 + k4];
            a0[n] = fmaf(xv.x, w0.x, a0[n]); a0[n] = fmaf(xv.y, w0.y, a0[n]);
            a0[n] = fmaf(xv.z, w0.z, a0[n]); a0[n] = fmaf(xv.w, w0.w, a0[n]);
            a1[n] = fmaf(xv.x, w1.x, a1[n]); a1[n] = fmaf(xv.y, w1.y, a1[n]);
            a1[n] = fmaf(xv.z, w1.z, a1[n]); a1[n] = fmaf(xv.w, w1.w, a1[n]);
            a2[n] = fmaf(xv.x, w2.x, a2[n]); a2[n] = fmaf(xv.y, w2.y, a2[n]);
            a2[n] = fmaf(xv.z, w2.z, a2[n]); a2[n] = fmaf(xv.w, w2.w, a2[n]);
            a3[n] = fmaf(xv.x, w3.x, a3[n]); a3[n] = fmaf(xv.y, w3.y, a3[n]);
            a3[n] = fmaf(xv.z, w3.z, a3[n]); a3[n] = fmaf(xv.w, w3.w, a3[n]);
        }
    }
#pragma unroll
    for (int n = 0; n < 16; n++) {
        size_t o = (size_t)(n0 + n) * 128;
        xr[o + t]         = a0[n];
        xr[o + t + 64]    = a1[n];
        xroot[o + t]      = a2[n];
        xroot[o + t + 64] = a3[n];
    }
}

// ---------------- fused agg(width128) + h = lrelu(agg + xroot + b1), float2 lanes ----------------
__global__ __launch_bounds__(64) void aggh_k(const float2* __restrict__ xr2,
        const float2* __restrict__ xroot2, const float* __restrict__ b1,
        const int* __restrict__ ptr, const int* __restrict__ ccol,
        float2* __restrict__ h2) {
    int r = blockIdx.x, j = threadIdx.x;
    int beg = ptr[r], end = ptr[r + 1];
    float sx0 = 0.f, sy0 = 0.f, sx1 = 0.f, sy1 = 0.f;
    float sx2 = 0.f, sy2 = 0.f, sx3 = 0.f, sy3 = 0.f;
    int e = beg;
    for (; e + 4 <= end; e += 4) {
        int c0 = ccol[e], c1 = ccol[e + 1], c2 = ccol[e + 2], c3 = ccol[e + 3];
        float2 v0 = xr2[(size_t)c0 * 64 + j];
        float2 v1 = xr2[(size_t)c1 * 64 + j];
        float2 v2 = xr2[(size_t)c2 * 64 + j];
        float2 v3 = xr2[(size_t)c3 * 64 + j];
        sx0 += v0.x; sy0 += v0.y; sx1 += v1.x; sy1 += v1.y;
        sx2 += v2.x; sy2 += v2.y; sx3 += v3.x; sy3 += v3.y;
    }
    for (; e < end; e++) {
        float2 v = xr2[(size_t)ccol[e] * 64 + j];
        sx0 += v.x; sy0 += v.y;
    }
    float2 xo = xroot2[(size_t)r * 64 + j];
    float hx = (sx0 + sx1) + (sx2 + sx3) + xo.x + b1[2 * j];
    float hy = (sy0 + sy1) + (sy2 + sy3) + xo.y + b1[2 * j + 1];
    hx = hx > 0.f ? hx : 0.2f * hx;
    hy = hy > 0.f ? hy : 0.2f * hy;
    h2[(size_t)r * 64 + j] = make_float2(hx, hy);
}

// ---------------- triple matmul: hr|hmu|hstd = h @ wt3 ; 16 nodes/block, LDS-staged ----------------
__global__ __launch_bounds__(64) void mm128x3_k(const float* __restrict__ h,
        const float4* __restrict__ wt4,
        float* __restrict__ hr, float* __restrict__ hmu, float* __restrict__ hstd) {
    __shared__ float4 sh4[512];    // 16 nodes x 32 float4 = 8 KB
    int t = threadIdx.x;
    int n0 = blockIdx.x * 16;
    const float4* hg = reinterpret_cast<const float4*>(h + (size_t)n0 * 128);
#pragma unroll
    for (int i = 0; i < 8; i++) sh4[i * 64 + t] = hg[i * 64 + t];
    __syncthreads();
    float a0[16] = {}, a1[16] = {}, a2[16] = {};
    for (int k4 = 0; k4 < 32; k4++) {
        float4 w0 = wt4[k4 * 192 + t];
        float4 w1 = wt4[k4 * 192 + t + 64];
        float4 w2 = wt4[k4 * 192 + t + 128];
#pragma unroll
        for (int n = 0; n < 16; n++) {
            float4 hv = sh4[n * 32 + k4];
            a0[n] = fmaf(hv.x, w0.x, a0[n]); a0[n] = fmaf(hv.y, w0.y, a0[n]);
            a0[n] = fmaf(hv.z, w0.z, a0[n]); a0[n] = fmaf(hv.w, w0.w, a0[n]);
            a1[n] = fmaf(hv.x, w1.x, a1[n]); a1[n] = fmaf(hv.y, w1.y, a1[n]);
            a1[n] = fmaf(hv.z, w1.z, a1[n]); a1[n] = fmaf(hv.w, w1.w, a1[n]);
            a2[n] = fmaf(hv.x, w2.x, a2[n]); a2[n] = fmaf(hv.y, w2.y, a2[n]);
            a2[n] = fmaf(hv.z, w2.z, a2[n]); a2[n] = fmaf(hv.w, w2.w, a2[n]);
        }
    }
#pragma unroll
    for (int n = 0; n < 16; n++) {
        size_t o = (size_t)(n0 + n) * 64 + t;
        hr[o] = a0[n]; hmu[o] = a1[n]; hstd[o] = a2[n];
    }
}

// ---------------- z-stage: agg(hr) + tanh/exp + outputs + row norm (4-deep MLP) ----------------
__global__ __launch_bounds__(64) void aggz_k(const float* __restrict__ hr,
        const float* __restrict__ hmu, const float* __restrict__ hstd,
        const float* __restrict__ b_mu, const float* __restrict__ b_std,
        const int* __restrict__ ptr, const int* __restrict__ ccol,
        float* __restrict__ z, float* __restrict__ out_z, float* __restrict__ out_zmu,
        float* __restrict__ out_zstd, float* __restrict__ nrm) {
    int r = blockIdx.x, j = threadIdx.x;
    int beg = ptr[r], end = ptr[r + 1];
    float a0 = 0.f, a1 = 0.f, a2 = 0.f, a3 = 0.f;
    int e = beg;
    for (; e + 4 <= end; e += 4) {
        int c0 = ccol[e], c1 = ccol[e + 1], c2 = ccol[e + 2], c3 = ccol[e + 3];
        a0 += hr[(size_t)c0 * 64 + j];
        a1 += hr[(size_t)c1 * 64 + j];
        a2 += hr[(size_t)c2 * 64 + j];
        a3 += hr[(size_t)c3 * 64 + j];
    }
    for (; e < end; e++) a0 += hr[(size_t)ccol[e] * 64 + j];
    float acc = (a0 + a1) + (a2 + a3);
    float zmu = tanhf(acc + hmu[(size_t)r * 64 + j] + b_mu[j]);
    float zls = tanhf(hstd[(size_t)r * 64 + j] + b_std[j]);
    float zstd = expf(zls);
    size_t o = (size_t)r * 64 + j;
    z[o] = zmu; out_z[o] = zmu; out_zmu[o] = zmu; out_zstd[o] = zstd;
    float s = zmu * zmu;
    s += __shfl_xor(s, 1); s += __shfl_xor(s, 2); s += __shfl_xor(s, 4);
    s += __shfl_xor(s, 8); s += __shfl_xor(s, 16); s += __shfl_xor(s, 32);
    if (j == 0) nrm[r] = fmaxf(sqrtf(s), 1e-8f);
}

// ---------------- edge cosine: 16 lanes per edge ----------------
__global__ __launch_bounds__(256) void edge_k(const float* __restrict__ z, const float* __restrict__ nrm,
        const int* __restrict__ row, const int* __restrict__ col, float* __restrict__ out, int E) {
    int t = threadIdx.x;
    int sub = t >> 4, off = t & 15;
    int e = blockIdx.x * 16 + sub;
    if (e >= E) return;
    int r = row[e], c = col[e];
    const float4* a = reinterpret_cast<const float4*>(z + (size_t)r * 64);
    const float4* b = reinterpret_cast<const float4*>(z + (size_t)c * 64);
    float4 av = a[off], bv = b[off];
    float s = av.x * bv.x + av.y * bv.y + av.z * bv.z + av.w * bv.w;
    s += __shfl_xor(s, 1); s += __shfl_xor(s, 2); s += __shfl_xor(s, 4); s += __shfl_xor(s, 8);
    if (off == 0) out[e] = s / (nrm[r] * nrm[c]);
}

// ---------------- dual matmul: zr|zroot = z @ wtg ; 16 nodes/block, LDS-staged ----------------
__global__ __launch_bounds__(64) void mm64x2_k(const float* __restrict__ z,
        const float4* __restrict__ wt4,
        float* __restrict__ zr, float* __restrict__ zroot) {
    __shared__ float4 sz4[256];    // 16 nodes x 16 float4 = 4 KB
    int t = threadIdx.x;
    int n0 = blockIdx.x * 16;
    const float4* zg = reinterpret_cast<const float4*>(z + (size_t)n0 * 64);
#pragma unroll
    for (int i = 0; i < 4; i++) sz4[i * 64 + t] = zg[i * 64 + t];
    __syncthreads();
    float a0[16] = {}, a1[16] = {};
    for (int k4 = 0; k4 < 16; k4++) {
        float4 w0 = wt4[k4 * 128 + t];
        float4 w1 = wt4[k4 * 128 + t + 64];
#pragma unroll
        for (int n = 0; n < 16; n++) {
            float4 zv = sz4[n * 16 + k4];
            a0[n] = fmaf(zv.x, w0.x, a0[n]); a0[n] = fmaf(zv.y, w0.y, a0[n]);
            a0[n] = fmaf(zv.z, w0.z, a0[n]); a0[n] = fmaf(zv.w, w0.w, a0[n]);
            a1[n] = fmaf(zv.x, w1.x, a1[n]); a1[n] = fmaf(zv.y, w1.y, a1[n]);
            a1[n] = fmaf(zv.z, w1.z, a1[n]); a1[n] = fmaf(zv.w, w1.w, a1[n]);
        }
    }
#pragma unroll
    for (int n = 0; n < 16; n++) {
        size_t o = (size_t)(n0 + n) * 64 + t;
        zr[o] = a0[n]; zroot[o] = a1[n];
    }
}

// ---------------- g1-stage (4-deep MLP) ----------------
__global__ __launch_bounds__(64) void g1gate_k(const float* __restrict__ zr, const float* __restrict__ zroot,
        const float* __restrict__ b_g1, const float* __restrict__ w_rel_g2,
        const float* __restrict__ w_root_g2,
        const int* __restrict__ ptr, const int* __restrict__ ccol,
        float* __restrict__ g1r, float* __restrict__ groot) {
    int r = blockIdx.x, j = threadIdx.x;
    int beg = ptr[r], end = ptr[r + 1];
    float a0 = 0.f, a1 = 0.f, a2 = 0.f, a3 = 0.f;
    int e = beg;
    for (; e + 4 <= end; e += 4) {
        int c0 = ccol[e], c1 = ccol[e + 1], c2 = ccol[e + 2], c3 = ccol[e + 3];
        a0 += zr[(size_t)c0 * 64 + j];
        a1 += zr[(size_t)c1 * 64 + j];
        a2 += zr[(size_t)c2 * 64 + j];
        a3 += zr[(size_t)c3 * 64 + j];
    }
    for (; e < end; e++) a0 += zr[(size_t)ccol[e] * 64 + j];
    float g = (a0 + a1) + (a2 + a3) + zroot[(size_t)r * 64 + j] + b_g1[j];
    g = g > 0.f ? g : 0.2f * g;
    float sr = g * w_rel_g2[j];
    float so = g * w_root_g2[j];
    sr += __shfl_xor(sr, 1); sr += __shfl_xor(sr, 2); sr += __shfl_xor(sr, 4);
    sr += __shfl_xor(sr, 8); sr += __shfl_xor(sr, 16); sr += __shfl_xor(sr, 32);
    so += __shfl_xor(so, 1); so += __shfl_xor(so, 2); so += __shfl_xor(so, 4);
    so += __shfl_xor(so, 8); so += __shfl_xor(so, 16); so += __shfl_xor(so, 32);
    if (j == 0) { g1r[r] = sr; groot[r] = so; }
}

// ---------------- gate assembly + partial max ----------------
__global__ __launch_bounds__(256) void gateagg_k(const float* __restrict__ g1r,
        const float* __restrict__ groot, const float* __restrict__ b_g2,
        const int* __restrict__ ptr, const int* __restrict__ ccol,
        float* __restrict__ gate, float* __restrict__ pmax, int N) {
    __shared__ float sm[256];
    float b = b_g2[0];
    float m = -3.4e38f;
    for (int r = blockIdx.x * blockDim.x + threadIdx.x; r < N; r += gridDim.x * blockDim.x) {
        int beg = ptr[r], end = ptr[r + 1];
        float s0 = 0.f, s1 = 0.f, s2 = 0.f, s3 = 0.f;
        int e = beg;
        for (; e + 4 <= end; e += 4) {
            s0 += g1r[ccol[e]]; s1 += g1r[ccol[e + 1]];
            s2 += g1r[ccol[e + 2]]; s3 += g1r[ccol[e + 3]];
        }
        for (; e < end; e++) s0 += g1r[ccol[e]];
        float g = (s0 + s1) + (s2 + s3) + groot[r] + b;
        gate[r] = g;
        m = fmaxf(m, g);
    }
    sm[threadIdx.x] = m;
    __syncthreads();
    for (int s2 = 128; s2 > 0; s2 >>= 1) {
        if (threadIdx.x < s2) sm[threadIdx.x] = fmaxf(sm[threadIdx.x], sm[threadIdx.x + s2]);
        __syncthreads();
    }
    if (threadIdx.x == 0) pmax[blockIdx.x] = sm[0];
}

__global__ void reduce_max_final(const float* __restrict__ pmax, float* __restrict__ smax) {
    float m = pmax[threadIdx.x];   // 64 threads, 64 partials
    for (int o = 32; o > 0; o >>= 1) m = fmaxf(m, __shfl_down(m, o));
    if (threadIdx.x == 0) smax[0] = m;
}

__global__ __launch_bounds__(256) void pooled_kernel(const float* __restrict__ gate,
        const float* __restrict__ smax, const float* __restrict__ z,
        float* __restrict__ pooled_num, float* __restrict__ wsum, int N) {
    int tid = threadIdx.x;
    int sub = tid >> 6, j = tid & 63;
    float mx = smax[0];
    float acc = 0.f, wsl = 0.f;
    for (int n = blockIdx.x * 4 + sub; n < N; n += gridDim.x * 4) {
        float w = expf(gate[n] - mx);
        acc = fmaf(w, z[(size_t)n * 64 + j], acc);
        if (j == 0) wsl += w;
    }
    __shared__ float lp[4][64];
    __shared__ float lw[4];
    lp[sub][j] = acc;
    if (j == 0) lw[sub] = wsl;
    __syncthreads();
    if (sub == 0) {
        float t = lp[0][j] + lp[1][j] + lp[2][j] + lp[3][j];
        atomicAdd(&pooled_num[j], t);
        if (j == 0) atomicAdd(wsum, lw[0] + lw[1] + lw[2] + lw[3]);
    }
}

__global__ void final_kernel(const float* __restrict__ pooled_num, const float* __restrict__ wsum,
                             const float* __restrict__ w_cls1, const float* __restrict__ b_cls1,
                             const float* __restrict__ w_cls2, const float* __restrict__ b_cls2,
                             const float* __restrict__ log_std,
                             float* __restrict__ out_y, float* __restrict__ out_wstd) {
    __shared__ float sp[64];
    __shared__ float st[64];
    int j = threadIdx.x;   // 64
    sp[j] = pooled_num[j] / wsum[0];
    __syncthreads();
    float acc = 0.f;
    const float* w = w_cls1 + j * 64;
#pragma unroll
    for (int k = 0; k < 64; k++) acc = fmaf(sp[k], w[k], acc);
    acc += b_cls1[j];
    st[j] = acc > 0.f ? acc : 0.2f * acc;
    __syncthreads();
    if (j == 0) {
        float l0 = b_cls2[0], l1 = b_cls2[1];
        for (int k = 0; k < 64; k++) {
            l0 = fmaf(st[k], w_cls2[k], l0);
            l1 = fmaf(st[k], w_cls2[64 + k], l1);
        }
        float m = fmaxf(l0, l1);
        float e0 = expf(l0 - m), e1 = expf(l1 - m);
        float s = e0 + e1;
        out_y[0] = e0 / s;
        out_y[1] = e1 / s;
        out_wstd[0] = expf(log_std[0]);
    }
}

extern "C" void kernel_launch(void* const* d_in, const int* in_sizes, int n_in,
                              void* d_out, int out_size, void* d_ws, size_t ws_size,
                              hipStream_t stream) {
    const int N = NN, E = EE;
    const float* x        = (const float*)d_in[0];
    const int*   row      = (const int*)d_in[1];
    const int*   col      = (const int*)d_in[2];
    const float* w_rel1   = (const float*)d_in[3];
    const float* w_root1  = (const float*)d_in[4];
    const float* b1       = (const float*)d_in[5];
    const float* w_rel_mu = (const float*)d_in[6];
    const float* w_root_mu= (const float*)d_in[7];
    const float* b_mu     = (const float*)d_in[8];
    const float* w_std    = (const float*)d_in[9];
    const float* b_std    = (const float*)d_in[10];
    const float* w_rel_g1 = (const float*)d_in[11];
    const float* w_root_g1= (const float*)d_in[12];
    const float* b_g1     = (const float*)d_in[13];
    const float* w_rel_g2 = (const float*)d_in[14];
    const float* w_root_g2= (const float*)d_in[15];
    const float* b_g2     = (const float*)d_in[16];
    const float* w_cls1   = (const float*)d_in[17];
    const float* b_cls1   = (const float*)d_in[18];
    const float* w_cls2   = (const float*)d_in[19];
    const float* b_cls2   = (const float*)d_in[20];
    const float* log_std  = (const float*)d_in[21];

    float* out = (float*)d_out;
    const long long OFF_WMU  = 2;
    const long long OFF_WSTD = 2 + (long long)E;
    const long long OFF_Z    = 3 + (long long)E;
    const long long OFF_ZMU  = OFF_Z + (long long)N * 64;
    const long long OFF_ZSTD = OFF_ZMU + (long long)N * 64;

    // ---- workspace layout (floats), ~95 MB total ----
    float* wsp = (float*)d_ws;
    float* R0   = wsp;                             // N*128 : xr    -> hstd (lo N*64)
    float* R1   = R0 + (size_t)N * 128;            // N*128 : xroot -> [hr | hmu]
    float* R2   = R1 + (size_t)N * 128;            // N*128 : h     -> [zr | zroot]
    float* R3   = R2 + (size_t)N * 128;            // N*64  : z
    float* R4   = R3 + (size_t)N * 64;             // 4N    : nrm, g1r, groot, gate
    float* R5   = R4 + (size_t)4 * N;              // 256   : pmax | smax | pooled | wsum
    float* wt1  = R5 + 256;                        // 65536
    float* wt3  = wt1 + 65536;                     // 24576
    float* wtg  = wt3 + 24576;                     // 8192
    int*   deg    = (int*)(wtg + 8192);            // N
    int*   ptr    = deg + N;                       // N+1 (pad 64)
    int*   cursor = ptr + N + 64;                  // N
    int*   ccol   = cursor + N;                    // E

    float* xr    = R0;
    float* hstd  = R0;
    float* xroot = R1;
    float* hr    = R1;
    float* hmu   = R1 + (size_t)N * 64;
    float* h     = R2;
    float* zr    = R2;
    float* zroot = R2 + (size_t)N * 64;
    float* zbuf  = R3;
    float* nrm   = R4;
    float* g1r   = R4 + N;
    float* groot = R4 + 2 * (size_t)N;
    float* gate  = R4 + 3 * (size_t)N;
    float* pmax  = R5;
    float* smax  = R5 + 64;
    float* pooled= R5 + 128;
    float* wsum  = R5 + 192;

    // ---- CSR build (shared by all 4 graph convs) ----
    hipMemsetAsync(deg, 0, (size_t)N * 4, stream);
    hist_k<<<(E + 255) / 256, 256, 0, stream>>>(row, deg, E);
    scan_k<<<1, 1024, 0, stream>>>(deg, ptr, cursor, N);
    place_k<<<(E + 255) / 256, 256, 0, stream>>>(row, col, cursor, ccol, E);

    // ---- combined transposed weights (k4-vectorized) ----
    transpose_all<<<384, 256, 0, stream>>>(w_rel1, w_root1, w_rel_mu, w_root_mu, w_std,
                                           w_rel_g1, w_root_g1, wt1, wt3, wtg);

    // ---- conv1 ----
    mm256_k<<<N / 16, 64, 0, stream>>>(x, (const float4*)wt1, xr, xroot);
    aggh_k<<<N, 64, 0, stream>>>((const float2*)xr, (const float2*)xroot, b1, ptr, ccol,
                                 (float2*)h);

    // ---- conv2 products ----
    mm128x3_k<<<N / 16, 64, 0, stream>>>(h, (const float4*)wt3, hr, hmu, hstd);

    // ---- z-stage (agg + tanh + outputs + norms) ----
    aggz_k<<<N, 64, 0, stream>>>(hr, hmu, hstd, b_mu, b_std, ptr, ccol,
                                 zbuf, out + OFF_Z, out + OFF_ZMU, out + OFF_ZSTD, nrm);

    // ---- per-edge cosine similarity ----
    edge_k<<<(E + 15) / 16, 256, 0, stream>>>(zbuf, nrm, row, col, out + OFF_WMU, E);

    // ---- attention pooling path ----
    mm64x2_k<<<N / 16, 64, 0, stream>>>(zbuf, (const float4*)wtg, zr, zroot);
    g1gate_k<<<N, 64, 0, stream>>>(zr, zroot, b_g1, w_rel_g2, w_root_g2, ptr, ccol, g1r, groot);
    gateagg_k<<<64, 256, 0, stream>>>(g1r, groot, b_g2, ptr, ccol, gate, pmax, N);
    reduce_max_final<<<1, 64, 0, stream>>>(pmax, smax);
    hipMemsetAsync(pooled, 0, 65 * 4, stream);
    pooled_kernel<<<128, 256, 0, stream>>>(gate, smax, zbuf, pooled, wsum, N);

    // ---- classifier + scalars ----
    final_kernel<<<1, 64, 0, stream>>>(pooled, wsum, w_cls1, b_cls1, w_cls2, b_cls2, log_std,
                                       out, out + OFF_WSTD);
}